// Round 1
// baseline (545.119 us; speedup 1.0000x reference)
//
#include <hip/hip_runtime.h>
#include <math.h>

#define N_NODES 50000
#define N_EDGES 800000
#define D 128
#define NBLK 196   // ceil(N_NODES/256)

typedef __attribute__((ext_vector_type(8))) short bf16x8;
typedef __attribute__((ext_vector_type(4))) float f32x4;

static __device__ __forceinline__ unsigned short f2bf(float f) {
    unsigned int u = __float_as_uint(f);
    u = (u + 0x7fffu + ((u >> 16) & 1u)) >> 16;
    return (unsigned short)u;
}
static __device__ __forceinline__ float bf2f(unsigned short h) {
    return __uint_as_float(((unsigned int)h) << 16);
}

// ---------------- fused prep: degree+rank histogram + split x + weight split-casts ----------------
__global__ void prep_deg_kernel(const int* __restrict__ dst, int* __restrict__ deg,
                                int* __restrict__ rank,
                                const float* __restrict__ x,
                                const float* __restrict__ W1l, const float* __restrict__ W1r,
                                const float* __restrict__ W2l, const float* __restrict__ W2r,
                                const float* __restrict__ Wlin,
                                unsigned short* __restrict__ xhi, unsigned short* __restrict__ xlo,
                                unsigned short* __restrict__ W1hi, unsigned short* __restrict__ W1lo,
                                unsigned short* __restrict__ W2hi, unsigned short* __restrict__ W2lo,
                                unsigned short* __restrict__ WLhi, unsigned short* __restrict__ WLlo) {
    int b = blockIdx.x, tid = threadIdx.x;
    if (b < 3125) {
        int e = b * 256 + tid;
        rank[e] = atomicAdd(&deg[dst[e]], 1);   // rank within dst bucket
    } else if (b < 9375) {
        int i = ((b - 3125) * 256 + tid) * 4;
        float4 v = *(const float4*)(x + i);
        ushort4 h, l;
        h.x = f2bf(v.x); l.x = f2bf(v.x - bf2f(h.x));
        h.y = f2bf(v.y); l.y = f2bf(v.y - bf2f(h.y));
        h.z = f2bf(v.z); l.z = f2bf(v.z - bf2f(h.z));
        h.w = f2bf(v.w); l.w = f2bf(v.w - bf2f(h.w));
        *(ushort4*)(xhi + i) = h;
        *(ushort4*)(xlo + i) = l;
    } else if (b < 9503) {
        int isW2 = (b >= 9439);
        const float* A = isW2 ? W2l : W1l;
        const float* B = isW2 ? W2r : W1r;
        unsigned short* hi = isW2 ? W2hi : W1hi;
        unsigned short* lo = isW2 ? W2lo : W1lo;
        int f = (b - (isW2 ? 9439 : 9375)) * 2 + (tid >> 7);
        int t = tid & 127;
        float va = A[f * 128 + t], vb = B[f * 128 + t];
        unsigned short ha = f2bf(va), hb = f2bf(vb);
        hi[f * 256 + t]       = ha;
        hi[f * 256 + 128 + t] = hb;
        lo[f * 256 + t]       = f2bf(va - bf2f(ha));
        lo[f * 256 + 128 + t] = f2bf(vb - bf2f(hb));
    } else {
        int f = b - 9503;
        float v = (f < 40) ? Wlin[f * 256 + tid] : 0.f;
        unsigned short h = f2bf(v);
        WLhi[f * 256 + tid] = h;
        WLlo[f * 256 + tid] = f2bf(v - bf2f(h));
    }
}

// ---------------- 2-stage scan ----------------
__global__ void scan_partial(const int* __restrict__ deg, int* __restrict__ bsum) {
    __shared__ int wt[4];
    int tid = threadIdx.x, lane = tid & 63, wv = tid >> 6;
    int idx = blockIdx.x * 256 + tid;
    int v = (idx < N_NODES) ? deg[idx] : 0;
    int s = v;
    #pragma unroll
    for (int o = 1; o < 64; o <<= 1) s += __shfl_xor(s, o, 64);
    if (lane == 0) wt[wv] = s;
    __syncthreads();
    if (tid == 0) bsum[blockIdx.x] = wt[0] + wt[1] + wt[2] + wt[3];
}

__global__ void scan_write(const int* __restrict__ deg, const int* __restrict__ bsum,
                           int* __restrict__ rowptr) {
    __shared__ int wt[4], wt2[4];
    int tid = threadIdx.x, lane = tid & 63, wv = tid >> 6;
    int v0 = (tid < blockIdx.x) ? bsum[tid] : 0;   // blockIdx.x <= 195 < 256
    int s0 = v0;
    #pragma unroll
    for (int o = 1; o < 64; o <<= 1) s0 += __shfl_xor(s0, o, 64);
    if (lane == 0) wt2[wv] = s0;
    int idx = blockIdx.x * 256 + tid;
    int v = (idx < N_NODES) ? deg[idx] : 0;
    int s = v;
    #pragma unroll
    for (int o = 1; o < 64; o <<= 1) { int t = __shfl_up(s, o, 64); if (lane >= o) s += t; }
    if (lane == 63) wt[wv] = s;
    __syncthreads();
    int boff = wt2[0] + wt2[1] + wt2[2] + wt2[3];
    #pragma unroll
    for (int w = 0; w < 4; w++) boff += (w < wv) ? wt[w] : 0;
    int excl = boff + s - v;
    if (idx < N_NODES) rowptr[idx] = excl;
    if (idx == 0) rowptr[N_NODES] = N_EDGES;
}

// ---------------- bucket edges by dst (atomic-free: pos = rowptr[dst] + rank) ----------------
__global__ void bucket_kernel(const int* __restrict__ src, const int* __restrict__ dst,
                              const int* __restrict__ rowptr, const int* __restrict__ rank,
                              int* __restrict__ srcs_sorted) {
    int e = blockIdx.x * blockDim.x + threadIdx.x;
    if (e < N_EDGES) {
        srcs_sorted[rowptr[dst[e]] + rank[e]] = src[e];
    }
}

// ---------------- fused layer: gather-mean (LDS) + split-bf16 MFMA GEMM ----------------
// Block = 512 thr (8 waves) = 64 nodes x 128 outputs.
// LDS 35840 B -> 4 blocks/CU (32 waves, whole 782-block grid resident in one round).
// W fragments are read directly from global (L2-resident, reused by every block) — the
// former 16 KB Wl staging buffer and its 7 per-block barriers are gone.
// rowptr for the block's 64 nodes is prefetched with 2 coalesced loads + shfl broadcast,
// removing 4 serial rowptr-load latencies from each wave's gather chain.
// Gather addresses use 32-bit byte offsets (saddr + voffset form: base is uniform, offset
// fits 12.8 MB) instead of 64-bit mad chains.
template<bool FINAL>
__global__ __launch_bounds__(512, 8) void fused_layer(
    const int* __restrict__ srcs, const int* __restrict__ rowptr,
    const unsigned short* __restrict__ Shi,                                     // gather source hi
    const unsigned short* __restrict__ A2hi, const unsigned short* __restrict__ A2lo,  // self planes
    const unsigned short* __restrict__ Whi, const unsigned short* __restrict__ Wlo,    // [128,256]
    const float* __restrict__ bias,
    unsigned short* __restrict__ Ohi, unsigned short* __restrict__ Olo,         // layer out (if !FINAL)
    const unsigned short* __restrict__ WLhi, const unsigned short* __restrict__ WLlo,  // [48,256]
    const float* __restrict__ blin, float* __restrict__ out)                    // (if FINAL)
{
    __shared__ unsigned int Ah[64 * 68];       // 17408 B (agg hi; reused as h2 hi if FINAL)
    __shared__ unsigned int Al[64 * 68];       // 17408 B
    __shared__ float stats[256];               // 1 KB softmax stats (FINAL)

    const int tid = threadIdx.x;
    const int wv = tid >> 6, lane = tid & 63;
    const int nb0 = blockIdx.x * 64;

    // prefetch rowptr bounds for all 64 nodes of this block (2 coalesced loads)
    const int nclamp = min(nb0 + lane, N_NODES - 1);
    const int rp0 = rowptr[nclamp];
    const int rp1 = rowptr[nclamp + 1];

    // ---- phase 1: gather-mean into LDS, 2-node interleaved streams ----
    const char* xb = (const char*)Shi;          // row = 256 bytes
    const int lb = lane << 2;
    #pragma unroll 1
    for (int it = 0; it < 4; it++) {
        int nlA = it * 16 + wv, nlB = nlA + 8;
        int begA = __shfl(rp0, nlA, 64), endA = __shfl(rp1, nlA, 64);
        int begB = __shfl(rp0, nlB, 64), endB = __shfl(rp1, nlB, 64);
        int nA = (endA - begA + 15) >> 4;
        int nB = (endB - begB + 15) >> 4;
        int nmax = max(nA, nB);
        float axA[4] = {0,0,0,0}, ayA[4] = {0,0,0,0};
        float axB[4] = {0,0,0,0}, ayB[4] = {0,0,0,0};
        #pragma unroll 1
        for (int b = 0; b < nmax; b++) {
            unsigned int uA[16], uB[16];
            int baseA = begA + b * 16, baseB = begB + b * 16;
            if (b < nA) {
                #pragma unroll
                for (int j = 0; j < 16; j++) {
                    int ee = min(baseA + j, endA - 1);
                    uA[j] = *(const unsigned int*)(xb + (((unsigned)srcs[ee] << 8) + lb));
                }
            }
            if (b < nB) {
                #pragma unroll
                for (int j = 0; j < 16; j++) {
                    int ee = min(baseB + j, endB - 1);
                    uB[j] = *(const unsigned int*)(xb + (((unsigned)srcs[ee] << 8) + lb));
                }
            }
            if (b < nA) {
                int cA = min(16, endA - baseA);
                #pragma unroll
                for (int j = 0; j < 16; j++) {
                    if (j < cA) {
                        axA[j & 3] += __uint_as_float(uA[j] << 16);
                        ayA[j & 3] += __uint_as_float(uA[j] & 0xffff0000u);
                    }
                }
            }
            if (b < nB) {
                int cB = min(16, endB - baseB);
                #pragma unroll
                for (int j = 0; j < 16; j++) {
                    if (j < cB) {
                        axB[j & 3] += __uint_as_float(uB[j] << 16);
                        ayB[j & 3] += __uint_as_float(uB[j] & 0xffff0000u);
                    }
                }
            }
        }
        {
            float sx = (axA[0] + axA[1]) + (axA[2] + axA[3]);
            float sy = (ayA[0] + ayA[1]) + (ayA[2] + ayA[3]);
            float inv = 1.0f / fmaxf((float)(endA - begA), 1.0f);
            sx *= inv; sy *= inv;
            unsigned short h0 = f2bf(sx), h1 = f2bf(sy);
            unsigned short l0 = f2bf(sx - bf2f(h0)), l1 = f2bf(sy - bf2f(h1));
            Ah[nlA * 68 + lane] = (unsigned int)h0 | ((unsigned int)h1 << 16);
            Al[nlA * 68 + lane] = (unsigned int)l0 | ((unsigned int)l1 << 16);
        }
        {
            float sx = (axB[0] + axB[1]) + (axB[2] + axB[3]);
            float sy = (ayB[0] + ayB[1]) + (ayB[2] + ayB[3]);
            float inv = 1.0f / fmaxf((float)(endB - begB), 1.0f);
            sx *= inv; sy *= inv;
            unsigned short h0 = f2bf(sx), h1 = f2bf(sy);
            unsigned short l0 = f2bf(sx - bf2f(h0)), l1 = f2bf(sy - bf2f(h1));
            Ah[nlB * 68 + lane] = (unsigned int)h0 | ((unsigned int)h1 << 16);
            Al[nlB * 68 + lane] = (unsigned int)l0 | ((unsigned int)l1 << 16);
        }
    }
    __syncthreads();   // A tiles ready

    const int m = lane & 15, quad = lane >> 4;
    const int g = wv & 3, tp = wv >> 2;
    const int node_base = nb0 + g * 16;
    const int nodec = min(node_base + m, N_NODES - 1);

    // A1 frags (agg, K 0..127) from LDS; A2 frags (self, K 128..255) from global
    bf16x8 a1h[4], a1l[4], a2h[4], a2l[4];
    {
        const unsigned short* r2h = A2hi + (size_t)nodec * D + quad * 8;
        const unsigned short* r2l = A2lo + (size_t)nodec * D + quad * 8;
        #pragma unroll
        for (int ks = 0; ks < 4; ks++) {
            a2h[ks] = *(const bf16x8*)(r2h + ks * 32);
            a2l[ks] = *(const bf16x8*)(r2l + ks * 32);
        }
        #pragma unroll
        for (int ks = 0; ks < 4; ks++) {
            int ad = ((g * 16 + m) * 68 + quad * 4 + ks * 16) * 2;   // ushort offset
            a1h[ks] = *(const bf16x8*)((const unsigned short*)Ah + ad);
            a1l[ks] = *(const bf16x8*)((const unsigned short*)Al + ad);
        }
    }
    if (FINAL) __syncthreads();   // all a1 frags in regs before any wave stashes h2 into Ah/Al

    // ---- phase 2: GEMM over 4 f-quarters, W fragments direct from global (L2-hot) ----
    #pragma unroll 1
    for (int fq = 0; fq < 4; fq++) {
        const int f = fq * 32 + tp * 16 + m;
        const unsigned short* whirow = Whi + (size_t)f * 256 + quad * 8;
        const unsigned short* wlorow = Wlo + (size_t)f * 256 + quad * 8;
        f32x4 acc0 = {0.f, 0.f, 0.f, 0.f};
        f32x4 acc1 = {0.f, 0.f, 0.f, 0.f};
        f32x4 acc2 = {0.f, 0.f, 0.f, 0.f};
        #pragma unroll
        for (int ks = 0; ks < 8; ks++) {
            bf16x8 bh = *(const bf16x8*)(whirow + ks * 32);
            bf16x8 bl = *(const bf16x8*)(wlorow + ks * 32);
            bf16x8 ah = (ks < 4) ? a1h[ks] : a2h[ks - 4];
            bf16x8 al = (ks < 4) ? a1l[ks] : a2l[ks - 4];
            acc0 = __builtin_amdgcn_mfma_f32_16x16x32_bf16(ah, bh, acc0, 0, 0, 0);
            acc1 = __builtin_amdgcn_mfma_f32_16x16x32_bf16(ah, bl, acc1, 0, 0, 0);
            acc2 = __builtin_amdgcn_mfma_f32_16x16x32_bf16(al, bh, acc2, 0, 0, 0);
        }
        float bv = bias[f];
        #pragma unroll
        for (int r = 0; r < 4; r++) {
            int lrow = g * 16 + quad * 4 + r;
            int nrow = nb0 + lrow;
            float v = fmaxf((acc0[r] + (acc1[r] + acc2[r])) + bv, 0.f);
            unsigned short h = f2bf(v);
            unsigned short l = f2bf(v - bf2f(h));
            if (FINAL) {
                // stash h2 in LDS (Ah/Al dead: a1 regs loaded before the barrier above)
                ((unsigned short*)Ah)[lrow * 136 + f] = h;
                ((unsigned short*)Al)[lrow * 136 + f] = l;
            } else if (nrow < N_NODES) {
                Ohi[(size_t)nrow * D + f] = h;
                Olo[(size_t)nrow * D + f] = l;
            }
        }
    }

    if (!FINAL) return;

    // ---- phase 3: classifier GEMM (48 cols) + log_softmax ----
    __syncthreads();   // h2 LDS complete
    bf16x8 a3h[4], a3l[4];
    #pragma unroll
    for (int ks = 0; ks < 4; ks++) {
        int ad = (g * 16 + m) * 136 + ks * 32 + quad * 8;
        a3h[ks] = *(const bf16x8*)((const unsigned short*)Ah + ad);
        a3l[ks] = *(const bf16x8*)((const unsigned short*)Al + ad);
    }
    // tp=0 -> tiles 0,1 (cols 0..31); tp=1 -> tile 2 (cols 32..47)
    const int ntiles = (tp == 0) ? 2 : 1;
    float res[2][4];
    #pragma unroll
    for (int t = 0; t < 2; t++) {
        if (t >= ntiles) break;
        int nt = (tp == 0) ? t : 2;
        int f = nt * 16 + m;
        const unsigned short* whirow = WLhi + (size_t)f * 256 + quad * 8;
        const unsigned short* wlorow = WLlo + (size_t)f * 256 + quad * 8;
        f32x4 acc0 = {0.f, 0.f, 0.f, 0.f};
        f32x4 acc1 = {0.f, 0.f, 0.f, 0.f};
        f32x4 acc2 = {0.f, 0.f, 0.f, 0.f};
        #pragma unroll
        for (int ks = 0; ks < 8; ks++) {
            bf16x8 bh = *(const bf16x8*)(whirow + ks * 32);
            bf16x8 bl = *(const bf16x8*)(wlorow + ks * 32);
            bf16x8 ah = (ks < 4) ? a2h[ks] : a3h[ks - 4];   // A = [h1 | h2]
            bf16x8 al = (ks < 4) ? a2l[ks] : a3l[ks - 4];
            acc0 = __builtin_amdgcn_mfma_f32_16x16x32_bf16(ah, bh, acc0, 0, 0, 0);
            acc1 = __builtin_amdgcn_mfma_f32_16x16x32_bf16(ah, bl, acc1, 0, 0, 0);
            acc2 = __builtin_amdgcn_mfma_f32_16x16x32_bf16(al, bh, acc2, 0, 0, 0);
        }
        float bv = (f < 40) ? blin[f] : 0.f;
        #pragma unroll
        for (int r = 0; r < 4; r++) res[t][r] = (acc0[r] + (acc1[r] + acc2[r])) + bv;
    }
    #pragma unroll
    for (int r = 0; r < 4; r++) {
        float pm = -INFINITY;
        #pragma unroll
        for (int t = 0; t < 2; t++) {
            if (t >= ntiles) break;
            int f = ((tp == 0) ? t : 2) * 16 + m;
            if (f < 40) pm = fmaxf(pm, res[t][r]);
        }
        #pragma unroll
        for (int o = 8; o > 0; o >>= 1) pm = fmaxf(pm, __shfl_xor(pm, o, 64));
        if (m == 0) stats[tp * 64 + g * 16 + quad * 4 + r] = pm;
    }
    __syncthreads();
    float gm[4];
    #pragma unroll
    for (int r = 0; r < 4; r++) {
        int row = g * 16 + quad * 4 + r;
        gm[r] = fmaxf(stats[row], stats[64 + row]);
        float ps = 0.f;
        #pragma unroll
        for (int t = 0; t < 2; t++) {
            if (t >= ntiles) break;
            int f = ((tp == 0) ? t : 2) * 16 + m;
            if (f < 40) ps += expf(res[t][r] - gm[r]);
        }
        #pragma unroll
        for (int o = 8; o > 0; o >>= 1) ps += __shfl_xor(ps, o, 64);
        if (m == 0) stats[128 + tp * 64 + row] = ps;
    }
    __syncthreads();
    #pragma unroll
    for (int r = 0; r < 4; r++) {
        int row = g * 16 + quad * 4 + r;
        int nrow = nb0 + row;
        if (nrow >= N_NODES) continue;
        float lse = gm[r] + logf(stats[128 + row] + stats[192 + row]);
        #pragma unroll
        for (int t = 0; t < 2; t++) {
            if (t >= ntiles) break;
            int f = ((tp == 0) ? t : 2) * 16 + m;
            if (f < 40) out[(size_t)nrow * 40 + f] = res[t][r] - lse;
        }
    }
}

extern "C" void kernel_launch(void* const* d_in, const int* in_sizes, int n_in,
                              void* d_out, int out_size, void* d_ws, size_t ws_size,
                              hipStream_t stream) {
    const float* x     = (const float*)d_in[0];
    const int*   ei    = (const int*)d_in[1];
    const int*   src   = ei;
    const int*   dst   = ei + N_EDGES;
    const float* W1_l  = (const float*)d_in[2];
    const float* b1_l  = (const float*)d_in[3];
    const float* W1_r  = (const float*)d_in[4];
    const float* W2_l  = (const float*)d_in[5];
    const float* b2_l  = (const float*)d_in[6];
    const float* W2_r  = (const float*)d_in[7];
    const float* W_lin = (const float*)d_in[8];
    const float* b_lin = (const float*)d_in[9];
    float* out = (float*)d_out;

    const size_t nd = (size_t)N_NODES * D;
    unsigned short* xhi  = (unsigned short*)d_ws;
    unsigned short* xlo  = xhi + nd;
    unsigned short* h1hi = xlo + nd;
    unsigned short* h1lo = h1hi + nd;
    unsigned short* W1hi = h1lo + nd;                // 128*256 bf16 each
    unsigned short* W1lo = W1hi + 128 * 256;
    unsigned short* W2hi = W1lo + 128 * 256;
    unsigned short* W2lo = W2hi + 128 * 256;
    unsigned short* WLhi = W2lo + 128 * 256;         // 48*256
    unsigned short* WLlo = WLhi + 48 * 256;
    int* deg    = (int*)(WLlo + 48 * 256);
    int* rowptr = deg + N_NODES;                     // N_NODES+1
    int* rank   = rowptr + N_NODES + 1;              // N_EDGES
    int* srcs_sorted = rank + N_EDGES;               // N_EDGES
    int* bsum   = srcs_sorted + N_EDGES;             // NBLK

    // ---- prep (casts/splits) + degree/rank histogram in one dispatch ----
    hipMemsetAsync(deg, 0, N_NODES * sizeof(int), stream);
    prep_deg_kernel<<<9551, 256, 0, stream>>>(dst, deg, rank, x, W1_l, W1_r, W2_l, W2_r, W_lin,
                                              xhi, xlo, W1hi, W1lo, W2hi, W2lo, WLhi, WLlo);

    // ---- CSR build ----
    scan_partial<<<NBLK, 256, 0, stream>>>(deg, bsum);
    scan_write<<<NBLK, 256, 0, stream>>>(deg, bsum, rowptr);
    bucket_kernel<<<(N_EDGES + 255) / 256, 256, 0, stream>>>(src, dst, rowptr, rank, srcs_sorted);

    const int lblk = (N_NODES + 63) / 64;

    // ---- layer 1: gather(x) + GEMM -> h1 planes ----
    fused_layer<false><<<lblk, 512, 0, stream>>>(srcs_sorted, rowptr, xhi, xhi, xlo,
                                                 W1hi, W1lo, b1_l, h1hi, h1lo,
                                                 nullptr, nullptr, nullptr, nullptr);
    // ---- layer 2 + classifier + log_softmax (h2 stays in LDS) ----
    fused_layer<true><<<lblk, 512, 0, stream>>>(srcs_sorted, rowptr, h1hi, h1hi, h1lo,
                                                W2hi, W2lo, b2_l, nullptr, nullptr,
                                                WLhi, WLlo, b_lin, out);
}

// Round 2
// 372.985 us; speedup vs baseline: 1.4615x; 1.4615x over previous
//
#include <hip/hip_runtime.h>
#include <math.h>

#define N_NODES 50000
#define N_EDGES 800000
#define D 128
#define NBLK 196   // ceil(N_NODES/256)

typedef __attribute__((ext_vector_type(8))) short bf16x8;
typedef __attribute__((ext_vector_type(4))) float f32x4;

static __device__ __forceinline__ unsigned short f2bf(float f) {
    unsigned int u = __float_as_uint(f);
    u = (u + 0x7fffu + ((u >> 16) & 1u)) >> 16;
    return (unsigned short)u;
}
static __device__ __forceinline__ float bf2f(unsigned short h) {
    return __uint_as_float(((unsigned int)h) << 16);
}

// ---------------- fused prep: degree+rank histogram + split x + weight split-casts ----------------
__global__ void prep_deg_kernel(const int* __restrict__ dst, int* __restrict__ deg,
                                int* __restrict__ rank,
                                const float* __restrict__ x,
                                const float* __restrict__ W1l, const float* __restrict__ W1r,
                                const float* __restrict__ W2l, const float* __restrict__ W2r,
                                const float* __restrict__ Wlin,
                                unsigned short* __restrict__ xhi, unsigned short* __restrict__ xlo,
                                unsigned short* __restrict__ W1hi, unsigned short* __restrict__ W1lo,
                                unsigned short* __restrict__ W2hi, unsigned short* __restrict__ W2lo,
                                unsigned short* __restrict__ WLhi, unsigned short* __restrict__ WLlo) {
    int b = blockIdx.x, tid = threadIdx.x;
    if (b < 3125) {
        int e = b * 256 + tid;
        rank[e] = atomicAdd(&deg[dst[e]], 1);   // rank within dst bucket
    } else if (b < 9375) {
        int i = ((b - 3125) * 256 + tid) * 4;
        float4 v = *(const float4*)(x + i);
        ushort4 h, l;
        h.x = f2bf(v.x); l.x = f2bf(v.x - bf2f(h.x));
        h.y = f2bf(v.y); l.y = f2bf(v.y - bf2f(h.y));
        h.z = f2bf(v.z); l.z = f2bf(v.z - bf2f(h.z));
        h.w = f2bf(v.w); l.w = f2bf(v.w - bf2f(h.w));
        *(ushort4*)(xhi + i) = h;
        *(ushort4*)(xlo + i) = l;
    } else if (b < 9503) {
        int isW2 = (b >= 9439);
        const float* A = isW2 ? W2l : W1l;
        const float* B = isW2 ? W2r : W1r;
        unsigned short* hi = isW2 ? W2hi : W1hi;
        unsigned short* lo = isW2 ? W2lo : W1lo;
        int f = (b - (isW2 ? 9439 : 9375)) * 2 + (tid >> 7);
        int t = tid & 127;
        float va = A[f * 128 + t], vb = B[f * 128 + t];
        unsigned short ha = f2bf(va), hb = f2bf(vb);
        hi[f * 256 + t]       = ha;
        hi[f * 256 + 128 + t] = hb;
        lo[f * 256 + t]       = f2bf(va - bf2f(ha));
        lo[f * 256 + 128 + t] = f2bf(vb - bf2f(hb));
    } else {
        int f = b - 9503;
        float v = (f < 40) ? Wlin[f * 256 + tid] : 0.f;
        unsigned short h = f2bf(v);
        WLhi[f * 256 + tid] = h;
        WLlo[f * 256 + tid] = f2bf(v - bf2f(h));
    }
}

// ---------------- 2-stage scan ----------------
__global__ void scan_partial(const int* __restrict__ deg, int* __restrict__ bsum) {
    __shared__ int wt[4];
    int tid = threadIdx.x, lane = tid & 63, wv = tid >> 6;
    int idx = blockIdx.x * 256 + tid;
    int v = (idx < N_NODES) ? deg[idx] : 0;
    int s = v;
    #pragma unroll
    for (int o = 1; o < 64; o <<= 1) s += __shfl_xor(s, o, 64);
    if (lane == 0) wt[wv] = s;
    __syncthreads();
    if (tid == 0) bsum[blockIdx.x] = wt[0] + wt[1] + wt[2] + wt[3];
}

__global__ void scan_write(const int* __restrict__ deg, const int* __restrict__ bsum,
                           int* __restrict__ rowptr) {
    __shared__ int wt[4], wt2[4];
    int tid = threadIdx.x, lane = tid & 63, wv = tid >> 6;
    int v0 = (tid < blockIdx.x) ? bsum[tid] : 0;   // blockIdx.x <= 195 < 256
    int s0 = v0;
    #pragma unroll
    for (int o = 1; o < 64; o <<= 1) s0 += __shfl_xor(s0, o, 64);
    if (lane == 0) wt2[wv] = s0;
    int idx = blockIdx.x * 256 + tid;
    int v = (idx < N_NODES) ? deg[idx] : 0;
    int s = v;
    #pragma unroll
    for (int o = 1; o < 64; o <<= 1) { int t = __shfl_up(s, o, 64); if (lane >= o) s += t; }
    if (lane == 63) wt[wv] = s;
    __syncthreads();
    int boff = wt2[0] + wt2[1] + wt2[2] + wt2[3];
    #pragma unroll
    for (int w = 0; w < 4; w++) boff += (w < wv) ? wt[w] : 0;
    int excl = boff + s - v;
    if (idx < N_NODES) rowptr[idx] = excl;
    if (idx == 0) rowptr[N_NODES] = N_EDGES;
}

// ---------------- bucket edges by dst (atomic-free: pos = rowptr[dst] + rank) ----------------
__global__ void bucket_kernel(const int* __restrict__ src, const int* __restrict__ dst,
                              const int* __restrict__ rowptr, const int* __restrict__ rank,
                              int* __restrict__ srcs_sorted) {
    int e = blockIdx.x * blockDim.x + threadIdx.x;
    if (e < N_EDGES) {
        srcs_sorted[rowptr[dst[e]] + rank[e]] = src[e];
    }
}

// ---------------- fused layer: gather-mean (LDS) + split-bf16 MFMA GEMM ----------------
// Block = 512 thr (8 waves) = 64 nodes x 128 outputs.
// LDS 35840 B (no W staging buffer); W fragments read directly from global (L2-resident,
// reused by all 782 blocks). rowptr prefetched via 2 coalesced loads + shfl broadcast.
// Gather uses 32-bit byte offsets (saddr+voffset form).
// __launch_bounds__(512, 4): VGPR cap 128. Round-1's (512,8) capped at 64 VGPRs and
// forced ~118 MB of scratch spill round-trips (WRITE_SIZE 7.8->126 MB) — never again.
// If the allocator lands <=64 VGPRs the HW still gives 4 blocks/CU on its own.
template<bool FINAL>
__global__ __launch_bounds__(512, 4) void fused_layer(
    const int* __restrict__ srcs, const int* __restrict__ rowptr,
    const unsigned short* __restrict__ Shi,                                     // gather source hi
    const unsigned short* __restrict__ A2hi, const unsigned short* __restrict__ A2lo,  // self planes
    const unsigned short* __restrict__ Whi, const unsigned short* __restrict__ Wlo,    // [128,256]
    const float* __restrict__ bias,
    unsigned short* __restrict__ Ohi, unsigned short* __restrict__ Olo,         // layer out (if !FINAL)
    const unsigned short* __restrict__ WLhi, const unsigned short* __restrict__ WLlo,  // [48,256]
    const float* __restrict__ blin, float* __restrict__ out)                    // (if FINAL)
{
    __shared__ unsigned int Ah[64 * 68];       // 17408 B (agg hi; reused as h2 hi if FINAL)
    __shared__ unsigned int Al[64 * 68];       // 17408 B
    __shared__ float stats[256];               // 1 KB softmax stats (FINAL)

    const int tid = threadIdx.x;
    const int wv = tid >> 6, lane = tid & 63;
    const int nb0 = blockIdx.x * 64;

    // prefetch rowptr bounds for all 64 nodes of this block (2 coalesced loads)
    const int nclamp = min(nb0 + lane, N_NODES - 1);
    const int rp0 = rowptr[nclamp];
    const int rp1 = rowptr[nclamp + 1];

    // ---- phase 1: gather-mean into LDS, 2-node interleaved streams ----
    const char* xb = (const char*)Shi;          // row = 256 bytes
    const int lb = lane << 2;
    #pragma unroll 1
    for (int it = 0; it < 4; it++) {
        int nlA = it * 16 + wv, nlB = nlA + 8;
        int begA = __shfl(rp0, nlA, 64), endA = __shfl(rp1, nlA, 64);
        int begB = __shfl(rp0, nlB, 64), endB = __shfl(rp1, nlB, 64);
        int nA = (endA - begA + 15) >> 4;
        int nB = (endB - begB + 15) >> 4;
        int nmax = max(nA, nB);
        float axA[4] = {0,0,0,0}, ayA[4] = {0,0,0,0};
        float axB[4] = {0,0,0,0}, ayB[4] = {0,0,0,0};
        #pragma unroll 1
        for (int b = 0; b < nmax; b++) {
            unsigned int uA[16], uB[16];
            int baseA = begA + b * 16, baseB = begB + b * 16;
            if (b < nA) {
                #pragma unroll
                for (int j = 0; j < 16; j++) {
                    int ee = min(baseA + j, endA - 1);
                    uA[j] = *(const unsigned int*)(xb + (((unsigned)srcs[ee] << 8) + lb));
                }
            }
            if (b < nB) {
                #pragma unroll
                for (int j = 0; j < 16; j++) {
                    int ee = min(baseB + j, endB - 1);
                    uB[j] = *(const unsigned int*)(xb + (((unsigned)srcs[ee] << 8) + lb));
                }
            }
            if (b < nA) {
                int cA = min(16, endA - baseA);
                #pragma unroll
                for (int j = 0; j < 16; j++) {
                    if (j < cA) {
                        axA[j & 3] += __uint_as_float(uA[j] << 16);
                        ayA[j & 3] += __uint_as_float(uA[j] & 0xffff0000u);
                    }
                }
            }
            if (b < nB) {
                int cB = min(16, endB - baseB);
                #pragma unroll
                for (int j = 0; j < 16; j++) {
                    if (j < cB) {
                        axB[j & 3] += __uint_as_float(uB[j] << 16);
                        ayB[j & 3] += __uint_as_float(uB[j] & 0xffff0000u);
                    }
                }
            }
        }
        {
            float sx = (axA[0] + axA[1]) + (axA[2] + axA[3]);
            float sy = (ayA[0] + ayA[1]) + (ayA[2] + ayA[3]);
            float inv = 1.0f / fmaxf((float)(endA - begA), 1.0f);
            sx *= inv; sy *= inv;
            unsigned short h0 = f2bf(sx), h1 = f2bf(sy);
            unsigned short l0 = f2bf(sx - bf2f(h0)), l1 = f2bf(sy - bf2f(h1));
            Ah[nlA * 68 + lane] = (unsigned int)h0 | ((unsigned int)h1 << 16);
            Al[nlA * 68 + lane] = (unsigned int)l0 | ((unsigned int)l1 << 16);
        }
        {
            float sx = (axB[0] + axB[1]) + (axB[2] + axB[3]);
            float sy = (ayB[0] + ayB[1]) + (ayB[2] + ayB[3]);
            float inv = 1.0f / fmaxf((float)(endB - begB), 1.0f);
            sx *= inv; sy *= inv;
            unsigned short h0 = f2bf(sx), h1 = f2bf(sy);
            unsigned short l0 = f2bf(sx - bf2f(h0)), l1 = f2bf(sy - bf2f(h1));
            Ah[nlB * 68 + lane] = (unsigned int)h0 | ((unsigned int)h1 << 16);
            Al[nlB * 68 + lane] = (unsigned int)l0 | ((unsigned int)l1 << 16);
        }
    }
    __syncthreads();   // A tiles ready

    const int m = lane & 15, quad = lane >> 4;
    const int g = wv & 3, tp = wv >> 2;
    const int node_base = nb0 + g * 16;
    const int nodec = min(node_base + m, N_NODES - 1);

    // A1 frags (agg, K 0..127) from LDS; A2 frags (self, K 128..255) from global
    bf16x8 a1h[4], a1l[4], a2h[4], a2l[4];
    {
        const unsigned short* r2h = A2hi + (size_t)nodec * D + quad * 8;
        const unsigned short* r2l = A2lo + (size_t)nodec * D + quad * 8;
        #pragma unroll
        for (int ks = 0; ks < 4; ks++) {
            a2h[ks] = *(const bf16x8*)(r2h + ks * 32);
            a2l[ks] = *(const bf16x8*)(r2l + ks * 32);
        }
        #pragma unroll
        for (int ks = 0; ks < 4; ks++) {
            int ad = ((g * 16 + m) * 68 + quad * 4 + ks * 16) * 2;   // ushort offset
            a1h[ks] = *(const bf16x8*)((const unsigned short*)Ah + ad);
            a1l[ks] = *(const bf16x8*)((const unsigned short*)Al + ad);
        }
    }
    if (FINAL) __syncthreads();   // all a1 frags in regs before any wave stashes h2 into Ah/Al

    // ---- phase 2: GEMM over 4 f-quarters, W fragments direct from global (L2-hot) ----
    #pragma unroll 1
    for (int fq = 0; fq < 4; fq++) {
        const int f = fq * 32 + tp * 16 + m;
        const unsigned short* whirow = Whi + (size_t)f * 256 + quad * 8;
        const unsigned short* wlorow = Wlo + (size_t)f * 256 + quad * 8;
        f32x4 acc0 = {0.f, 0.f, 0.f, 0.f};
        f32x4 acc1 = {0.f, 0.f, 0.f, 0.f};
        f32x4 acc2 = {0.f, 0.f, 0.f, 0.f};
        #pragma unroll
        for (int ks = 0; ks < 8; ks++) {
            bf16x8 bh = *(const bf16x8*)(whirow + ks * 32);
            bf16x8 bl = *(const bf16x8*)(wlorow + ks * 32);
            bf16x8 ah = (ks < 4) ? a1h[ks] : a2h[ks - 4];
            bf16x8 al = (ks < 4) ? a1l[ks] : a2l[ks - 4];
            acc0 = __builtin_amdgcn_mfma_f32_16x16x32_bf16(ah, bh, acc0, 0, 0, 0);
            acc1 = __builtin_amdgcn_mfma_f32_16x16x32_bf16(ah, bl, acc1, 0, 0, 0);
            acc2 = __builtin_amdgcn_mfma_f32_16x16x32_bf16(al, bh, acc2, 0, 0, 0);
        }
        float bv = bias[f];
        #pragma unroll
        for (int r = 0; r < 4; r++) {
            int lrow = g * 16 + quad * 4 + r;
            int nrow = nb0 + lrow;
            float v = fmaxf((acc0[r] + (acc1[r] + acc2[r])) + bv, 0.f);
            unsigned short h = f2bf(v);
            unsigned short l = f2bf(v - bf2f(h));
            if (FINAL) {
                // stash h2 in LDS (Ah/Al dead: a1 regs loaded before the barrier above)
                ((unsigned short*)Ah)[lrow * 136 + f] = h;
                ((unsigned short*)Al)[lrow * 136 + f] = l;
            } else if (nrow < N_NODES) {
                Ohi[(size_t)nrow * D + f] = h;
                Olo[(size_t)nrow * D + f] = l;
            }
        }
    }

    if (!FINAL) return;

    // ---- phase 3: classifier GEMM (48 cols) + log_softmax ----
    __syncthreads();   // h2 LDS complete
    bf16x8 a3h[4], a3l[4];
    #pragma unroll
    for (int ks = 0; ks < 4; ks++) {
        int ad = (g * 16 + m) * 136 + ks * 32 + quad * 8;
        a3h[ks] = *(const bf16x8*)((const unsigned short*)Ah + ad);
        a3l[ks] = *(const bf16x8*)((const unsigned short*)Al + ad);
    }
    // tp=0 -> tiles 0,1 (cols 0..31); tp=1 -> tile 2 (cols 32..47)
    const int ntiles = (tp == 0) ? 2 : 1;
    float res[2][4];
    #pragma unroll
    for (int t = 0; t < 2; t++) {
        if (t >= ntiles) break;
        int nt = (tp == 0) ? t : 2;
        int f = nt * 16 + m;
        const unsigned short* whirow = WLhi + (size_t)f * 256 + quad * 8;
        const unsigned short* wlorow = WLlo + (size_t)f * 256 + quad * 8;
        f32x4 acc0 = {0.f, 0.f, 0.f, 0.f};
        f32x4 acc1 = {0.f, 0.f, 0.f, 0.f};
        f32x4 acc2 = {0.f, 0.f, 0.f, 0.f};
        #pragma unroll
        for (int ks = 0; ks < 8; ks++) {
            bf16x8 bh = *(const bf16x8*)(whirow + ks * 32);
            bf16x8 bl = *(const bf16x8*)(wlorow + ks * 32);
            bf16x8 ah = (ks < 4) ? a2h[ks] : a3h[ks - 4];   // A = [h1 | h2]
            bf16x8 al = (ks < 4) ? a2l[ks] : a3l[ks - 4];
            acc0 = __builtin_amdgcn_mfma_f32_16x16x32_bf16(ah, bh, acc0, 0, 0, 0);
            acc1 = __builtin_amdgcn_mfma_f32_16x16x32_bf16(ah, bl, acc1, 0, 0, 0);
            acc2 = __builtin_amdgcn_mfma_f32_16x16x32_bf16(al, bh, acc2, 0, 0, 0);
        }
        float bv = (f < 40) ? blin[f] : 0.f;
        #pragma unroll
        for (int r = 0; r < 4; r++) res[t][r] = (acc0[r] + (acc1[r] + acc2[r])) + bv;
    }
    #pragma unroll
    for (int r = 0; r < 4; r++) {
        float pm = -INFINITY;
        #pragma unroll
        for (int t = 0; t < 2; t++) {
            if (t >= ntiles) break;
            int f = ((tp == 0) ? t : 2) * 16 + m;
            if (f < 40) pm = fmaxf(pm, res[t][r]);
        }
        #pragma unroll
        for (int o = 8; o > 0; o >>= 1) pm = fmaxf(pm, __shfl_xor(pm, o, 64));
        if (m == 0) stats[tp * 64 + g * 16 + quad * 4 + r] = pm;
    }
    __syncthreads();
    float gm[4];
    #pragma unroll
    for (int r = 0; r < 4; r++) {
        int row = g * 16 + quad * 4 + r;
        gm[r] = fmaxf(stats[row], stats[64 + row]);
        float ps = 0.f;
        #pragma unroll
        for (int t = 0; t < 2; t++) {
            if (t >= ntiles) break;
            int f = ((tp == 0) ? t : 2) * 16 + m;
            if (f < 40) ps += expf(res[t][r] - gm[r]);
        }
        #pragma unroll
        for (int o = 8; o > 0; o >>= 1) ps += __shfl_xor(ps, o, 64);
        if (m == 0) stats[128 + tp * 64 + row] = ps;
    }
    __syncthreads();
    #pragma unroll
    for (int r = 0; r < 4; r++) {
        int row = g * 16 + quad * 4 + r;
        int nrow = nb0 + row;
        if (nrow >= N_NODES) continue;
        float lse = gm[r] + logf(stats[128 + row] + stats[192 + row]);
        #pragma unroll
        for (int t = 0; t < 2; t++) {
            if (t >= ntiles) break;
            int f = ((tp == 0) ? t : 2) * 16 + m;
            if (f < 40) out[(size_t)nrow * 40 + f] = res[t][r] - lse;
        }
    }
}

extern "C" void kernel_launch(void* const* d_in, const int* in_sizes, int n_in,
                              void* d_out, int out_size, void* d_ws, size_t ws_size,
                              hipStream_t stream) {
    const float* x     = (const float*)d_in[0];
    const int*   ei    = (const int*)d_in[1];
    const int*   src   = ei;
    const int*   dst   = ei + N_EDGES;
    const float* W1_l  = (const float*)d_in[2];
    const float* b1_l  = (const float*)d_in[3];
    const float* W1_r  = (const float*)d_in[4];
    const float* W2_l  = (const float*)d_in[5];
    const float* b2_l  = (const float*)d_in[6];
    const float* W2_r  = (const float*)d_in[7];
    const float* W_lin = (const float*)d_in[8];
    const float* b_lin = (const float*)d_in[9];
    float* out = (float*)d_out;

    const size_t nd = (size_t)N_NODES * D;
    unsigned short* xhi  = (unsigned short*)d_ws;
    unsigned short* xlo  = xhi + nd;
    unsigned short* h1hi = xlo + nd;
    unsigned short* h1lo = h1hi + nd;
    unsigned short* W1hi = h1lo + nd;                // 128*256 bf16 each
    unsigned short* W1lo = W1hi + 128 * 256;
    unsigned short* W2hi = W1lo + 128 * 256;
    unsigned short* W2lo = W2hi + 128 * 256;
    unsigned short* WLhi = W2lo + 128 * 256;         // 48*256
    unsigned short* WLlo = WLhi + 48 * 256;
    int* deg    = (int*)(WLlo + 48 * 256);
    int* rowptr = deg + N_NODES;                     // N_NODES+1
    int* rank   = rowptr + N_NODES + 1;              // N_EDGES
    int* srcs_sorted = rank + N_EDGES;               // N_EDGES
    int* bsum   = srcs_sorted + N_EDGES;             // NBLK

    // ---- prep (casts/splits) + degree/rank histogram in one dispatch ----
    hipMemsetAsync(deg, 0, N_NODES * sizeof(int), stream);
    prep_deg_kernel<<<9551, 256, 0, stream>>>(dst, deg, rank, x, W1_l, W1_r, W2_l, W2_r, W_lin,
                                              xhi, xlo, W1hi, W1lo, W2hi, W2lo, WLhi, WLlo);

    // ---- CSR build ----
    scan_partial<<<NBLK, 256, 0, stream>>>(deg, bsum);
    scan_write<<<NBLK, 256, 0, stream>>>(deg, bsum, rowptr);
    bucket_kernel<<<(N_EDGES + 255) / 256, 256, 0, stream>>>(src, dst, rowptr, rank, srcs_sorted);

    const int lblk = (N_NODES + 63) / 64;

    // ---- layer 1: gather(x) + GEMM -> h1 planes ----
    fused_layer<false><<<lblk, 512, 0, stream>>>(srcs_sorted, rowptr, xhi, xhi, xlo,
                                                 W1hi, W1lo, b1_l, h1hi, h1lo,
                                                 nullptr, nullptr, nullptr, nullptr);
    // ---- layer 2 + classifier + log_softmax (h2 stays in LDS) ----
    fused_layer<true><<<lblk, 512, 0, stream>>>(srcs_sorted, rowptr, h1hi, h1hi, h1lo,
                                                W2hi, W2lo, b2_l, nullptr, nullptr,
                                                WLhi, WLlo, b_lin, out);
}

// Round 3
// 339.683 us; speedup vs baseline: 1.6048x; 1.0980x over previous
//
#include <hip/hip_runtime.h>
#include <math.h>

#define N_NODES 50000
#define N_EDGES 800000
#define D 128
#define NBLK 196   // ceil(N_NODES/256)

typedef __attribute__((ext_vector_type(8))) short bf16x8;
typedef __attribute__((ext_vector_type(4))) float f32x4;
typedef __attribute__((ext_vector_type(4))) unsigned int u32x4;

static __device__ __forceinline__ unsigned short f2bf(float f) {
    unsigned int u = __float_as_uint(f);
    u = (u + 0x7fffu + ((u >> 16) & 1u)) >> 16;
    return (unsigned short)u;
}
static __device__ __forceinline__ float bf2f(unsigned short h) {
    return __uint_as_float(((unsigned int)h) << 16);
}

// ---------------- fused prep: degree+rank histogram + split x + weight split-casts ----------------
__global__ void prep_deg_kernel(const int* __restrict__ dst, int* __restrict__ deg,
                                int* __restrict__ rank,
                                const float* __restrict__ x,
                                const float* __restrict__ W1l, const float* __restrict__ W1r,
                                const float* __restrict__ W2l, const float* __restrict__ W2r,
                                const float* __restrict__ Wlin,
                                unsigned short* __restrict__ xhi, unsigned short* __restrict__ xlo,
                                unsigned short* __restrict__ W1hi, unsigned short* __restrict__ W1lo,
                                unsigned short* __restrict__ W2hi, unsigned short* __restrict__ W2lo,
                                unsigned short* __restrict__ WLhi, unsigned short* __restrict__ WLlo) {
    int b = blockIdx.x, tid = threadIdx.x;
    if (b < 3125) {
        int e = b * 256 + tid;
        rank[e] = atomicAdd(&deg[dst[e]], 1);   // rank within dst bucket
    } else if (b < 9375) {
        int i = ((b - 3125) * 256 + tid) * 4;
        float4 v = *(const float4*)(x + i);
        ushort4 h, l;
        h.x = f2bf(v.x); l.x = f2bf(v.x - bf2f(h.x));
        h.y = f2bf(v.y); l.y = f2bf(v.y - bf2f(h.y));
        h.z = f2bf(v.z); l.z = f2bf(v.z - bf2f(h.z));
        h.w = f2bf(v.w); l.w = f2bf(v.w - bf2f(h.w));
        *(ushort4*)(xhi + i) = h;
        *(ushort4*)(xlo + i) = l;
    } else if (b < 9503) {
        int isW2 = (b >= 9439);
        const float* A = isW2 ? W2l : W1l;
        const float* B = isW2 ? W2r : W1r;
        unsigned short* hi = isW2 ? W2hi : W1hi;
        unsigned short* lo = isW2 ? W2lo : W1lo;
        int f = (b - (isW2 ? 9439 : 9375)) * 2 + (tid >> 7);
        int t = tid & 127;
        float va = A[f * 128 + t], vb = B[f * 128 + t];
        unsigned short ha = f2bf(va), hb = f2bf(vb);
        hi[f * 256 + t]       = ha;
        hi[f * 256 + 128 + t] = hb;
        lo[f * 256 + t]       = f2bf(va - bf2f(ha));
        lo[f * 256 + 128 + t] = f2bf(vb - bf2f(hb));
    } else {
        int f = b - 9503;
        float v = (f < 40) ? Wlin[f * 256 + tid] : 0.f;
        unsigned short h = f2bf(v);
        WLhi[f * 256 + tid] = h;
        WLlo[f * 256 + tid] = f2bf(v - bf2f(h));
    }
}

// ---------------- 2-stage scan ----------------
__global__ void scan_partial(const int* __restrict__ deg, int* __restrict__ bsum) {
    __shared__ int wt[4];
    int tid = threadIdx.x, lane = tid & 63, wv = tid >> 6;
    int idx = blockIdx.x * 256 + tid;
    int v = (idx < N_NODES) ? deg[idx] : 0;
    int s = v;
    #pragma unroll
    for (int o = 1; o < 64; o <<= 1) s += __shfl_xor(s, o, 64);
    if (lane == 0) wt[wv] = s;
    __syncthreads();
    if (tid == 0) bsum[blockIdx.x] = wt[0] + wt[1] + wt[2] + wt[3];
}

__global__ void scan_write(const int* __restrict__ deg, const int* __restrict__ bsum,
                           int* __restrict__ rowptr) {
    __shared__ int wt[4], wt2[4];
    int tid = threadIdx.x, lane = tid & 63, wv = tid >> 6;
    int v0 = (tid < blockIdx.x) ? bsum[tid] : 0;   // blockIdx.x <= 195 < 256
    int s0 = v0;
    #pragma unroll
    for (int o = 1; o < 64; o <<= 1) s0 += __shfl_xor(s0, o, 64);
    if (lane == 0) wt2[wv] = s0;
    int idx = blockIdx.x * 256 + tid;
    int v = (idx < N_NODES) ? deg[idx] : 0;
    int s = v;
    #pragma unroll
    for (int o = 1; o < 64; o <<= 1) { int t = __shfl_up(s, o, 64); if (lane >= o) s += t; }
    if (lane == 63) wt[wv] = s;
    __syncthreads();
    int boff = wt2[0] + wt2[1] + wt2[2] + wt2[3];
    #pragma unroll
    for (int w = 0; w < 4; w++) boff += (w < wv) ? wt[w] : 0;
    int excl = boff + s - v;
    if (idx < N_NODES) rowptr[idx] = excl;
    if (idx == 0) rowptr[N_NODES] = N_EDGES;
}

// ---------------- bucket edges by dst (atomic-free: pos = rowptr[dst] + rank) ----------------
__global__ void bucket_kernel(const int* __restrict__ src, const int* __restrict__ dst,
                              const int* __restrict__ rowptr, const int* __restrict__ rank,
                              int* __restrict__ srcs_sorted) {
    int e = blockIdx.x * blockDim.x + threadIdx.x;
    if (e < N_EDGES) {
        srcs_sorted[rowptr[dst[e]] + rank[e]] = src[e];
    }
}

// ---------------- fused layer: gather-mean (LDS) + split-bf16 MFMA GEMM ----------------
// Block = 512 thr (8 waves) = 64 nodes x 128 outputs. LDS 51 KB, 3 blocks/CU.
// GEMM: baseline structure (Whi staged 16 KB/quarter in LDS — round-2 A/B showed
// direct-global B-hi fragments cost +19 us at this occupancy).
// Gather (new): dwordx4 rows. 16 lanes cover one 256 B row -> one wave-instr fetches
// 4 edge rows (4x fewer VMEM instrs, 4x bytes per TA slot). srcs prefetched 64-at-a-time
// into regs (coalesced) and broadcast via shfl — removes the per-edge broadcast load and
// its serial latency. Edges padded to 4 (not 16): issue waste ~43% -> ~9%.
// Cross-group (lane^16, lane^32) shfl-reduce combines the 4 groups' partial sums.
template<bool FINAL>
__global__ __launch_bounds__(512, 4) void fused_layer(
    const int* __restrict__ srcs, const int* __restrict__ rowptr,
    const unsigned short* __restrict__ Shi,                                     // gather source hi
    const unsigned short* __restrict__ A2hi, const unsigned short* __restrict__ A2lo,  // self planes
    const unsigned short* __restrict__ Whi, const unsigned short* __restrict__ Wlo,    // [128,256]
    const float* __restrict__ bias,
    unsigned short* __restrict__ Ohi, unsigned short* __restrict__ Olo,         // layer out (if !FINAL)
    const unsigned short* __restrict__ WLhi, const unsigned short* __restrict__ WLlo,  // [48,256]
    const float* __restrict__ blin, float* __restrict__ out)                    // (if FINAL)
{
    __shared__ unsigned int Ah[64 * 68];       // 17408 B (agg hi; reused as h2 hi if FINAL)
    __shared__ unsigned int Al[64 * 68];       // 17408 B
    __shared__ unsigned short Wl[8192];        // 16 KB (Whi quarter stage)
    __shared__ float stats[256];               // 1 KB softmax stats (FINAL)

    const int tid = threadIdx.x;
    const int wv = tid >> 6, lane = tid & 63;
    const int nb0 = blockIdx.x * 64;

    // prefetch rowptr bounds for all 64 nodes of this block (2 coalesced loads)
    const int nclamp = min(nb0 + lane, N_NODES - 1);
    const int rp0 = rowptr[nclamp];
    const int rp1 = rowptr[nclamp + 1];

    // ---- phase 1: gather-mean into LDS, 2-node interleaved streams, dwordx4 rows ----
    const char* xb = (const char*)Shi;          // row = 256 bytes
    const int g = lane >> 4;                    // edge group (4 edges per wave-instr)
    const int q = lane & 15;                    // feature quarter (16 B of the row)
    const int qb = q << 4;
    #pragma unroll 1
    for (int it = 0; it < 4; it++) {
        int nlA = it * 16 + wv, nlB = nlA + 8;
        int begA = __shfl(rp0, nlA, 64), endA = __shfl(rp1, nlA, 64);
        int begB = __shfl(rp0, nlB, 64), endB = __shfl(rp1, nlB, 64);
        int degA = endA - begA, degB = endB - begB;
        float ax[4] = {0,0,0,0}, ay[4] = {0,0,0,0};
        float bx[4] = {0,0,0,0}, by[4] = {0,0,0,0};
        int nsA = (degA + 63) >> 6, nsB = (degB + 63) >> 6;
        int nsmax = max(nsA, nsB);
        #pragma unroll 1
        for (int st = 0; st < nsmax; st++) {
            int svA = 0, svB = 0;
            int nbA = 0, nbB = 0;
            if (st < nsA) {                     // wave-uniform branch
                int sb = begA + (st << 6);
                nbA = min(64, endA - sb);
                svA = srcs[min(sb + lane, endA - 1)];   // 64 edge ids, coalesced
            }
            if (st < nsB) {
                int sb = begB + (st << 6);
                nbB = min(64, endB - sb);
                svB = srcs[min(sb + lane, endB - 1)];
            }
            int itA = (nbA + 3) >> 2, itB = (nbB + 3) >> 2;
            int itmax = max(itA, itB);
            #pragma unroll 4
            for (int b = 0; b < itmax; b++) {
                int ei = (b << 2) + g;          // edge slot within strip for this group
                if (b < itA) {                  // wave-uniform
                    unsigned srcv = (unsigned)__shfl(svA, ei, 64);
                    u32x4 v = *(const u32x4*)(xb + ((srcv << 8) + qb));
                    v.x = (ei < nbA) ? v.x : 0u;
                    v.y = (ei < nbA) ? v.y : 0u;
                    v.z = (ei < nbA) ? v.z : 0u;
                    v.w = (ei < nbA) ? v.w : 0u;
                    ax[0] += __uint_as_float(v.x << 16); ay[0] += __uint_as_float(v.x & 0xffff0000u);
                    ax[1] += __uint_as_float(v.y << 16); ay[1] += __uint_as_float(v.y & 0xffff0000u);
                    ax[2] += __uint_as_float(v.z << 16); ay[2] += __uint_as_float(v.z & 0xffff0000u);
                    ax[3] += __uint_as_float(v.w << 16); ay[3] += __uint_as_float(v.w & 0xffff0000u);
                }
                if (b < itB) {
                    unsigned srcv = (unsigned)__shfl(svB, ei, 64);
                    u32x4 v = *(const u32x4*)(xb + ((srcv << 8) + qb));
                    v.x = (ei < nbB) ? v.x : 0u;
                    v.y = (ei < nbB) ? v.y : 0u;
                    v.z = (ei < nbB) ? v.z : 0u;
                    v.w = (ei < nbB) ? v.w : 0u;
                    bx[0] += __uint_as_float(v.x << 16); by[0] += __uint_as_float(v.x & 0xffff0000u);
                    bx[1] += __uint_as_float(v.y << 16); by[1] += __uint_as_float(v.y & 0xffff0000u);
                    bx[2] += __uint_as_float(v.z << 16); by[2] += __uint_as_float(v.z & 0xffff0000u);
                    bx[3] += __uint_as_float(v.w << 16); by[3] += __uint_as_float(v.w & 0xffff0000u);
                }
            }
        }
        // cross-group reduce: lanes {l, l^16, l^32, l^48} hold partials of the same features
        #pragma unroll
        for (int d = 0; d < 4; d++) {
            ax[d] += __shfl_xor(ax[d], 16, 64); ax[d] += __shfl_xor(ax[d], 32, 64);
            ay[d] += __shfl_xor(ay[d], 16, 64); ay[d] += __shfl_xor(ay[d], 32, 64);
            bx[d] += __shfl_xor(bx[d], 16, 64); bx[d] += __shfl_xor(bx[d], 32, 64);
            by[d] += __shfl_xor(by[d], 16, 64); by[d] += __shfl_xor(by[d], 32, 64);
        }
        if (g == 0) {   // 16 lanes write 4 dwords each: one ds_write_b128 per plane
            float invA = 1.0f / fmaxf((float)degA, 1.0f);
            float invB = 1.0f / fmaxf((float)degB, 1.0f);
            u32x4 ha, la, hb, lb;
            #pragma unroll
            for (int d = 0; d < 4; d++) {
                float sx = ax[d] * invA, sy = ay[d] * invA;
                unsigned short h0 = f2bf(sx), h1 = f2bf(sy);
                unsigned short l0 = f2bf(sx - bf2f(h0)), l1 = f2bf(sy - bf2f(h1));
                ha[d] = (unsigned)h0 | ((unsigned)h1 << 16);
                la[d] = (unsigned)l0 | ((unsigned)l1 << 16);
                float tx = bx[d] * invB, ty = by[d] * invB;
                unsigned short h2 = f2bf(tx), h3 = f2bf(ty);
                unsigned short l2 = f2bf(tx - bf2f(h2)), l3 = f2bf(ty - bf2f(h3));
                hb[d] = (unsigned)h2 | ((unsigned)h3 << 16);
                lb[d] = (unsigned)l2 | ((unsigned)l3 << 16);
            }
            *(u32x4*)&Ah[nlA * 68 + q * 4] = ha;
            *(u32x4*)&Al[nlA * 68 + q * 4] = la;
            *(u32x4*)&Ah[nlB * 68 + q * 4] = hb;
            *(u32x4*)&Al[nlB * 68 + q * 4] = lb;
        }
    }
    __syncthreads();   // A tiles ready

    const int m = lane & 15, quad = lane >> 4;
    const int gg = wv & 3, tp = wv >> 2;
    const int node_base = nb0 + gg * 16;
    const int nodec = min(node_base + m, N_NODES - 1);

    // A1 frags (agg, K 0..127) from LDS; A2 frags (self, K 128..255) from global
    bf16x8 a1h[4], a1l[4], a2h[4], a2l[4];
    {
        const unsigned short* r2h = A2hi + (size_t)nodec * D + quad * 8;
        const unsigned short* r2l = A2lo + (size_t)nodec * D + quad * 8;
        #pragma unroll
        for (int ks = 0; ks < 4; ks++) {
            a2h[ks] = *(const bf16x8*)(r2h + ks * 32);
            a2l[ks] = *(const bf16x8*)(r2l + ks * 32);
        }
        #pragma unroll
        for (int ks = 0; ks < 4; ks++) {
            int ad = ((gg * 16 + m) * 68 + quad * 4 + ks * 16) * 2;   // ushort offset
            a1h[ks] = *(const bf16x8*)((const unsigned short*)Ah + ad);
            a1l[ks] = *(const bf16x8*)((const unsigned short*)Al + ad);
        }
    }

    // ---- phase 2: GEMM over 4 f-quarters (Whi staged 16 KB at a time) ----
    #pragma unroll 1
    for (int fq = 0; fq < 4; fq++) {
        const int f0 = fq * 32;
        if (fq) __syncthreads();
        #pragma unroll
        for (int itS = 0; itS < 2; itS++) {
            int c = tid + itS * 512;                 // 1024 chunks of 16B
            int nt = c >> 9, w2 = c & 511;
            int ks = w2 >> 6, lidx = w2 & 63;
            int mm = lidx >> 2, qq = lidx & 3;
            const unsigned short* gp = Whi + (size_t)(f0 + nt * 16 + mm) * 256 + ks * 32 + qq * 8;
            *(bf16x8*)&Wl[(size_t)c * 8] = *(const bf16x8*)gp;
        }
        __syncthreads();

        int f = f0 + tp * 16 + m;
        const unsigned short* wlorow = Wlo + (size_t)f * 256 + quad * 8;
        f32x4 acc0 = {0.f, 0.f, 0.f, 0.f};
        f32x4 acc1 = {0.f, 0.f, 0.f, 0.f};
        f32x4 acc2 = {0.f, 0.f, 0.f, 0.f};
        #pragma unroll
        for (int ks = 0; ks < 8; ks++) {
            bf16x8 bh = *(const bf16x8*)&Wl[(size_t)(((tp * 8 + ks) << 6) + (m * 4 + quad)) * 8];
            bf16x8 bl = *(const bf16x8*)(wlorow + ks * 32);
            bf16x8 ah = (ks < 4) ? a1h[ks] : a2h[ks - 4];
            bf16x8 al = (ks < 4) ? a1l[ks] : a2l[ks - 4];
            acc0 = __builtin_amdgcn_mfma_f32_16x16x32_bf16(ah, bh, acc0, 0, 0, 0);
            acc1 = __builtin_amdgcn_mfma_f32_16x16x32_bf16(ah, bl, acc1, 0, 0, 0);
            acc2 = __builtin_amdgcn_mfma_f32_16x16x32_bf16(al, bh, acc2, 0, 0, 0);
        }
        float bv = bias[f];
        #pragma unroll
        for (int r = 0; r < 4; r++) {
            int lrow = gg * 16 + quad * 4 + r;
            int nrow = nb0 + lrow;
            float v = fmaxf((acc0[r] + (acc1[r] + acc2[r])) + bv, 0.f);
            unsigned short h = f2bf(v);
            unsigned short l = f2bf(v - bf2f(h));
            if (FINAL) {
                // stash h2 in LDS (Ah/Al dead: a1 regs loaded before the fq0 staging barrier)
                ((unsigned short*)Ah)[lrow * 136 + f] = h;
                ((unsigned short*)Al)[lrow * 136 + f] = l;
            } else if (nrow < N_NODES) {
                Ohi[(size_t)nrow * D + f] = h;
                Olo[(size_t)nrow * D + f] = l;
            }
        }
    }

    if (!FINAL) return;

    // ---- phase 3: classifier GEMM (48 cols) + log_softmax ----
    __syncthreads();   // h2 LDS complete
    bf16x8 a3h[4], a3l[4];
    #pragma unroll
    for (int ks = 0; ks < 4; ks++) {
        int ad = (gg * 16 + m) * 136 + ks * 32 + quad * 8;
        a3h[ks] = *(const bf16x8*)((const unsigned short*)Ah + ad);
        a3l[ks] = *(const bf16x8*)((const unsigned short*)Al + ad);
    }
    // tp=0 -> tiles 0,1 (cols 0..31); tp=1 -> tile 2 (cols 32..47)
    const int ntiles = (tp == 0) ? 2 : 1;
    float res[2][4];
    #pragma unroll
    for (int t = 0; t < 2; t++) {
        if (t >= ntiles) break;
        int nt = (tp == 0) ? t : 2;
        int f = nt * 16 + m;
        const unsigned short* whirow = WLhi + (size_t)f * 256 + quad * 8;
        const unsigned short* wlorow = WLlo + (size_t)f * 256 + quad * 8;
        f32x4 acc0 = {0.f, 0.f, 0.f, 0.f};
        f32x4 acc1 = {0.f, 0.f, 0.f, 0.f};
        f32x4 acc2 = {0.f, 0.f, 0.f, 0.f};
        #pragma unroll
        for (int ks = 0; ks < 8; ks++) {
            bf16x8 bh = *(const bf16x8*)(whirow + ks * 32);
            bf16x8 bl = *(const bf16x8*)(wlorow + ks * 32);
            bf16x8 ah = (ks < 4) ? a2h[ks] : a3h[ks - 4];   // A = [h1 | h2]
            bf16x8 al = (ks < 4) ? a2l[ks] : a3l[ks - 4];
            acc0 = __builtin_amdgcn_mfma_f32_16x16x32_bf16(ah, bh, acc0, 0, 0, 0);
            acc1 = __builtin_amdgcn_mfma_f32_16x16x32_bf16(ah, bl, acc1, 0, 0, 0);
            acc2 = __builtin_amdgcn_mfma_f32_16x16x32_bf16(al, bh, acc2, 0, 0, 0);
        }
        float bv = (f < 40) ? blin[f] : 0.f;
        #pragma unroll
        for (int r = 0; r < 4; r++) res[t][r] = (acc0[r] + (acc1[r] + acc2[r])) + bv;
    }
    #pragma unroll
    for (int r = 0; r < 4; r++) {
        float pm = -INFINITY;
        #pragma unroll
        for (int t = 0; t < 2; t++) {
            if (t >= ntiles) break;
            int f = ((tp == 0) ? t : 2) * 16 + m;
            if (f < 40) pm = fmaxf(pm, res[t][r]);
        }
        #pragma unroll
        for (int o = 8; o > 0; o >>= 1) pm = fmaxf(pm, __shfl_xor(pm, o, 64));
        if (m == 0) stats[tp * 64 + gg * 16 + quad * 4 + r] = pm;
    }
    __syncthreads();
    float gm[4];
    #pragma unroll
    for (int r = 0; r < 4; r++) {
        int row = gg * 16 + quad * 4 + r;
        gm[r] = fmaxf(stats[row], stats[64 + row]);
        float ps = 0.f;
        #pragma unroll
        for (int t = 0; t < 2; t++) {
            if (t >= ntiles) break;
            int f = ((tp == 0) ? t : 2) * 16 + m;
            if (f < 40) ps += expf(res[t][r] - gm[r]);
        }
        #pragma unroll
        for (int o = 8; o > 0; o >>= 1) ps += __shfl_xor(ps, o, 64);
        if (m == 0) stats[128 + tp * 64 + row] = ps;
    }
    __syncthreads();
    #pragma unroll
    for (int r = 0; r < 4; r++) {
        int row = gg * 16 + quad * 4 + r;
        int nrow = nb0 + row;
        if (nrow >= N_NODES) continue;
        float lse = gm[r] + logf(stats[128 + row] + stats[192 + row]);
        #pragma unroll
        for (int t = 0; t < 2; t++) {
            if (t >= ntiles) break;
            int f = ((tp == 0) ? t : 2) * 16 + m;
            if (f < 40) out[(size_t)nrow * 40 + f] = res[t][r] - lse;
        }
    }
}

extern "C" void kernel_launch(void* const* d_in, const int* in_sizes, int n_in,
                              void* d_out, int out_size, void* d_ws, size_t ws_size,
                              hipStream_t stream) {
    const float* x     = (const float*)d_in[0];
    const int*   ei    = (const int*)d_in[1];
    const int*   src   = ei;
    const int*   dst   = ei + N_EDGES;
    const float* W1_l  = (const float*)d_in[2];
    const float* b1_l  = (const float*)d_in[3];
    const float* W1_r  = (const float*)d_in[4];
    const float* W2_l  = (const float*)d_in[5];
    const float* b2_l  = (const float*)d_in[6];
    const float* W2_r  = (const float*)d_in[7];
    const float* W_lin = (const float*)d_in[8];
    const float* b_lin = (const float*)d_in[9];
    float* out = (float*)d_out;

    const size_t nd = (size_t)N_NODES * D;
    unsigned short* xhi  = (unsigned short*)d_ws;
    unsigned short* xlo  = xhi + nd;
    unsigned short* h1hi = xlo + nd;
    unsigned short* h1lo = h1hi + nd;
    unsigned short* W1hi = h1lo + nd;                // 128*256 bf16 each
    unsigned short* W1lo = W1hi + 128 * 256;
    unsigned short* W2hi = W1lo + 128 * 256;
    unsigned short* W2lo = W2hi + 128 * 256;
    unsigned short* WLhi = W2lo + 128 * 256;         // 48*256
    unsigned short* WLlo = WLhi + 48 * 256;
    int* deg    = (int*)(WLlo + 48 * 256);
    int* rowptr = deg + N_NODES;                     // N_NODES+1
    int* rank   = rowptr + N_NODES + 1;              // N_EDGES
    int* srcs_sorted = rank + N_EDGES;               // N_EDGES
    int* bsum   = srcs_sorted + N_EDGES;             // NBLK

    // ---- prep (casts/splits) + degree/rank histogram in one dispatch ----
    hipMemsetAsync(deg, 0, N_NODES * sizeof(int), stream);
    prep_deg_kernel<<<9551, 256, 0, stream>>>(dst, deg, rank, x, W1_l, W1_r, W2_l, W2_r, W_lin,
                                              xhi, xlo, W1hi, W1lo, W2hi, W2lo, WLhi, WLlo);

    // ---- CSR build ----
    scan_partial<<<NBLK, 256, 0, stream>>>(deg, bsum);
    scan_write<<<NBLK, 256, 0, stream>>>(deg, bsum, rowptr);
    bucket_kernel<<<(N_EDGES + 255) / 256, 256, 0, stream>>>(src, dst, rowptr, rank, srcs_sorted);

    const int lblk = (N_NODES + 63) / 64;

    // ---- layer 1: gather(x) + GEMM -> h1 planes ----
    fused_layer<false><<<lblk, 512, 0, stream>>>(srcs_sorted, rowptr, xhi, xhi, xlo,
                                                 W1hi, W1lo, b1_l, h1hi, h1lo,
                                                 nullptr, nullptr, nullptr, nullptr);
    // ---- layer 2 + classifier + log_softmax (h2 stays in LDS) ----
    fused_layer<true><<<lblk, 512, 0, stream>>>(srcs_sorted, rowptr, h1hi, h1hi, h1lo,
                                                W2hi, W2lo, b2_l, nullptr, nullptr,
                                                WLhi, WLlo, b_lin, out);
}

// Round 4
// 329.341 us; speedup vs baseline: 1.6552x; 1.0314x over previous
//
#include <hip/hip_runtime.h>
#include <math.h>

#define N_NODES 50000
#define N_EDGES 800000
#define D 128
#define NBLK 196   // ceil(N_NODES/256)
#define GATHER_BLOCKS 2048

typedef __attribute__((ext_vector_type(8))) short bf16x8;
typedef __attribute__((ext_vector_type(4))) float f32x4;
typedef __attribute__((ext_vector_type(4))) unsigned int u32x4;

static __device__ __forceinline__ unsigned short f2bf(float f) {
    unsigned int u = __float_as_uint(f);
    u = (u + 0x7fffu + ((u >> 16) & 1u)) >> 16;
    return (unsigned short)u;
}
static __device__ __forceinline__ float bf2f(unsigned short h) {
    return __uint_as_float(((unsigned int)h) << 16);
}

// ---------------- fused prep: degree+rank histogram + split x + weight split-casts ----------------
__global__ void prep_deg_kernel(const int* __restrict__ dst, int* __restrict__ deg,
                                int* __restrict__ rank,
                                const float* __restrict__ x,
                                const float* __restrict__ W1l, const float* __restrict__ W1r,
                                const float* __restrict__ W2l, const float* __restrict__ W2r,
                                const float* __restrict__ Wlin,
                                unsigned short* __restrict__ xhi, unsigned short* __restrict__ xlo,
                                unsigned short* __restrict__ W1hi, unsigned short* __restrict__ W1lo,
                                unsigned short* __restrict__ W2hi, unsigned short* __restrict__ W2lo,
                                unsigned short* __restrict__ WLhi, unsigned short* __restrict__ WLlo) {
    int b = blockIdx.x, tid = threadIdx.x;
    if (b < 3125) {
        int e = b * 256 + tid;
        rank[e] = atomicAdd(&deg[dst[e]], 1);   // rank within dst bucket
    } else if (b < 9375) {
        int i = ((b - 3125) * 256 + tid) * 4;
        float4 v = *(const float4*)(x + i);
        ushort4 h, l;
        h.x = f2bf(v.x); l.x = f2bf(v.x - bf2f(h.x));
        h.y = f2bf(v.y); l.y = f2bf(v.y - bf2f(h.y));
        h.z = f2bf(v.z); l.z = f2bf(v.z - bf2f(h.z));
        h.w = f2bf(v.w); l.w = f2bf(v.w - bf2f(h.w));
        *(ushort4*)(xhi + i) = h;
        *(ushort4*)(xlo + i) = l;
    } else if (b < 9503) {
        int isW2 = (b >= 9439);
        const float* A = isW2 ? W2l : W1l;
        const float* B = isW2 ? W2r : W1r;
        unsigned short* hi = isW2 ? W2hi : W1hi;
        unsigned short* lo = isW2 ? W2lo : W1lo;
        int f = (b - (isW2 ? 9439 : 9375)) * 2 + (tid >> 7);
        int t = tid & 127;
        float va = A[f * 128 + t], vb = B[f * 128 + t];
        unsigned short ha = f2bf(va), hb = f2bf(vb);
        hi[f * 256 + t]       = ha;
        hi[f * 256 + 128 + t] = hb;
        lo[f * 256 + t]       = f2bf(va - bf2f(ha));
        lo[f * 256 + 128 + t] = f2bf(vb - bf2f(hb));
    } else {
        int f = b - 9503;
        float v = (f < 40) ? Wlin[f * 256 + tid] : 0.f;
        unsigned short h = f2bf(v);
        WLhi[f * 256 + tid] = h;
        WLlo[f * 256 + tid] = f2bf(v - bf2f(h));
    }
}

// ---------------- 2-stage scan ----------------
__global__ void scan_partial(const int* __restrict__ deg, int* __restrict__ bsum) {
    __shared__ int wt[4];
    int tid = threadIdx.x, lane = tid & 63, wv = tid >> 6;
    int idx = blockIdx.x * 256 + tid;
    int v = (idx < N_NODES) ? deg[idx] : 0;
    int s = v;
    #pragma unroll
    for (int o = 1; o < 64; o <<= 1) s += __shfl_xor(s, o, 64);
    if (lane == 0) wt[wv] = s;
    __syncthreads();
    if (tid == 0) bsum[blockIdx.x] = wt[0] + wt[1] + wt[2] + wt[3];
}

__global__ void scan_write(const int* __restrict__ deg, const int* __restrict__ bsum,
                           int* __restrict__ rowptr) {
    __shared__ int wt[4], wt2[4];
    int tid = threadIdx.x, lane = tid & 63, wv = tid >> 6;
    int v0 = (tid < blockIdx.x) ? bsum[tid] : 0;   // blockIdx.x <= 195 < 256
    int s0 = v0;
    #pragma unroll
    for (int o = 1; o < 64; o <<= 1) s0 += __shfl_xor(s0, o, 64);
    if (lane == 0) wt2[wv] = s0;
    int idx = blockIdx.x * 256 + tid;
    int v = (idx < N_NODES) ? deg[idx] : 0;
    int s = v;
    #pragma unroll
    for (int o = 1; o < 64; o <<= 1) { int t = __shfl_up(s, o, 64); if (lane >= o) s += t; }
    if (lane == 63) wt[wv] = s;
    __syncthreads();
    int boff = wt2[0] + wt2[1] + wt2[2] + wt2[3];
    #pragma unroll
    for (int w = 0; w < 4; w++) boff += (w < wv) ? wt[w] : 0;
    int excl = boff + s - v;
    if (idx < N_NODES) rowptr[idx] = excl;
    if (idx == 0) rowptr[N_NODES] = N_EDGES;
}

// ---------------- bucket edges by dst (atomic-free: pos = rowptr[dst] + rank) ----------------
__global__ void bucket_kernel(const int* __restrict__ src, const int* __restrict__ dst,
                              const int* __restrict__ rowptr, const int* __restrict__ rank,
                              int* __restrict__ srcs_sorted) {
    int e = blockIdx.x * blockDim.x + threadIdx.x;
    if (e < N_EDGES) {
        srcs_sorted[rowptr[dst[e]] + rank[e]] = src[e];
    }
}

// ---------------- gather-mean kernel (split out: no LDS -> 32 waves/CU) ----------------
// 16 lanes cover one 256 B row (dwordx4); 4 rows per wave-instr; 2-node (A/B adjacent,
// so rowptr[nB]=rowptr[nA+1] shares a load and srcs strips are contiguous) x unroll-2
// streams ~ 64 lines in flight per wave. Writes agg mean as hi+lo bf16 planes (coalesced).
__global__ __launch_bounds__(256, 8) void gather_mean(
    const int* __restrict__ srcs, const int* __restrict__ rowptr,
    const unsigned short* __restrict__ Shi,
    unsigned short* __restrict__ Aghi, unsigned short* __restrict__ Aglo)
{
    const int tid = threadIdx.x;
    const int wv = tid >> 6, lane = tid & 63;
    const int g = lane >> 4, q = lane & 15;
    const int qb = q << 4;
    const char* xb = (const char*)Shi;          // row = 256 bytes
    const int wid = blockIdx.x * 4 + wv;
    const int NW = GATHER_BLOCKS * 4;
    #pragma unroll 1
    for (int p = wid; p < N_NODES / 2; p += NW) {
        const int nA = 2 * p, nB = 2 * p + 1;
        const int begA = rowptr[nA];
        const int endA = rowptr[nA + 1];
        const int endB = rowptr[nB + 1];
        const int begB = endA;
        const int degA = endA - begA, degB = endB - begB;
        float ax[4] = {0,0,0,0}, ay[4] = {0,0,0,0};
        float bx[4] = {0,0,0,0}, by[4] = {0,0,0,0};
        int nsA = (degA + 63) >> 6, nsB = (degB + 63) >> 6;
        int nsmax = max(nsA, nsB);
        #pragma unroll 1
        for (int st = 0; st < nsmax; st++) {
            int svA = 0, svB = 0, nbA = 0, nbB = 0;
            if (st < nsA) {                     // wave-uniform branch
                int sb = begA + (st << 6);
                nbA = min(64, endA - sb);
                svA = srcs[min(sb + lane, endA - 1)];   // 64 edge ids, coalesced
            }
            if (st < nsB) {
                int sb = begB + (st << 6);
                nbB = min(64, endB - sb);
                svB = srcs[min(sb + lane, endB - 1)];
            }
            int itA = (nbA + 3) >> 2, itB = (nbB + 3) >> 2;
            int itmax = max(itA, itB);
            #pragma unroll 2
            for (int b = 0; b < itmax; b++) {
                int ei = (b << 2) + g;          // edge slot within strip for this group
                if (b < itA) {                  // wave-uniform
                    unsigned sv = (unsigned)__shfl(svA, ei, 64);
                    u32x4 v = *(const u32x4*)(xb + ((sv << 8) + qb));
                    v.x = (ei < nbA) ? v.x : 0u;
                    v.y = (ei < nbA) ? v.y : 0u;
                    v.z = (ei < nbA) ? v.z : 0u;
                    v.w = (ei < nbA) ? v.w : 0u;
                    ax[0] += __uint_as_float(v.x << 16); ay[0] += __uint_as_float(v.x & 0xffff0000u);
                    ax[1] += __uint_as_float(v.y << 16); ay[1] += __uint_as_float(v.y & 0xffff0000u);
                    ax[2] += __uint_as_float(v.z << 16); ay[2] += __uint_as_float(v.z & 0xffff0000u);
                    ax[3] += __uint_as_float(v.w << 16); ay[3] += __uint_as_float(v.w & 0xffff0000u);
                }
                if (b < itB) {
                    unsigned sv = (unsigned)__shfl(svB, ei, 64);
                    u32x4 v = *(const u32x4*)(xb + ((sv << 8) + qb));
                    v.x = (ei < nbB) ? v.x : 0u;
                    v.y = (ei < nbB) ? v.y : 0u;
                    v.z = (ei < nbB) ? v.z : 0u;
                    v.w = (ei < nbB) ? v.w : 0u;
                    bx[0] += __uint_as_float(v.x << 16); by[0] += __uint_as_float(v.x & 0xffff0000u);
                    bx[1] += __uint_as_float(v.y << 16); by[1] += __uint_as_float(v.y & 0xffff0000u);
                    bx[2] += __uint_as_float(v.z << 16); by[2] += __uint_as_float(v.z & 0xffff0000u);
                    bx[3] += __uint_as_float(v.w << 16); by[3] += __uint_as_float(v.w & 0xffff0000u);
                }
            }
        }
        // cross-group reduce: lanes {l, l^16, l^32, l^48} hold partials of the same features
        #pragma unroll
        for (int d = 0; d < 4; d++) {
            ax[d] += __shfl_xor(ax[d], 16, 64); ax[d] += __shfl_xor(ax[d], 32, 64);
            ay[d] += __shfl_xor(ay[d], 16, 64); ay[d] += __shfl_xor(ay[d], 32, 64);
            bx[d] += __shfl_xor(bx[d], 16, 64); bx[d] += __shfl_xor(bx[d], 32, 64);
            by[d] += __shfl_xor(by[d], 16, 64); by[d] += __shfl_xor(by[d], 32, 64);
        }
        if (g == 0) {   // 16 lanes write one u32x4 per plane per node (coalesced 256 B)
            float invA = 1.0f / fmaxf((float)degA, 1.0f);
            float invB = 1.0f / fmaxf((float)degB, 1.0f);
            u32x4 ha, la, hb, lb;
            #pragma unroll
            for (int d = 0; d < 4; d++) {
                float sx = ax[d] * invA, sy = ay[d] * invA;
                unsigned short h0 = f2bf(sx), h1 = f2bf(sy);
                unsigned short l0 = f2bf(sx - bf2f(h0)), l1 = f2bf(sy - bf2f(h1));
                ha[d] = (unsigned)h0 | ((unsigned)h1 << 16);
                la[d] = (unsigned)l0 | ((unsigned)l1 << 16);
                float tx = bx[d] * invB, ty = by[d] * invB;
                unsigned short h2 = f2bf(tx), h3 = f2bf(ty);
                unsigned short l2 = f2bf(tx - bf2f(h2)), l3 = f2bf(ty - bf2f(h3));
                hb[d] = (unsigned)h2 | ((unsigned)h3 << 16);
                lb[d] = (unsigned)l2 | ((unsigned)l3 << 16);
            }
            *(u32x4*)(Aghi + (size_t)nA * D + q * 8) = ha;
            *(u32x4*)(Aglo + (size_t)nA * D + q * 8) = la;
            *(u32x4*)(Aghi + (size_t)nB * D + q * 8) = hb;
            *(u32x4*)(Aglo + (size_t)nB * D + q * 8) = lb;
        }
    }
}

// ---------------- GEMM kernel: split-bf16 MFMA, A-frags straight from HBM ----------------
// Block = 512 thr (8 waves) = 64 nodes x 128 outputs. Non-final LDS ~17.4 KB -> 4 blocks/CU.
// Whi staged in LDS (round-2 A/B: direct scattered global B-hi cost +19 us).
// FINAL fuses classifier + log_softmax; h2 stashed in LDS (52 KB -> 3 blocks/CU).
template<bool FINAL>
__global__ __launch_bounds__(512, 4) void gemm_layer(
    const unsigned short* __restrict__ Aghi, const unsigned short* __restrict__ Aglo,  // agg planes
    const unsigned short* __restrict__ A2hi, const unsigned short* __restrict__ A2lo,  // self planes
    const unsigned short* __restrict__ Whi, const unsigned short* __restrict__ Wlo,    // [128,256]
    const float* __restrict__ bias,
    unsigned short* __restrict__ Ohi, unsigned short* __restrict__ Olo,         // layer out (if !FINAL)
    const unsigned short* __restrict__ WLhi, const unsigned short* __restrict__ WLlo,  // [48,256]
    const float* __restrict__ blin, float* __restrict__ out)                    // (if FINAL)
{
    __shared__ unsigned short Wl[8192];                 // 16 KB (Whi quarter stage)
    __shared__ unsigned int Ah[FINAL ? 64 * 68 : 1];    // h2 hi stash (FINAL only)
    __shared__ unsigned int Al[FINAL ? 64 * 68 : 1];
    __shared__ float stats[256];                        // softmax stats (FINAL)

    const int tid = threadIdx.x;
    const int wv = tid >> 6, lane = tid & 63;
    const int nb0 = blockIdx.x * 64;
    const int m = lane & 15, quad = lane >> 4;
    const int gg = wv & 3, tp = wv >> 2;
    const int nodec = min(nb0 + gg * 16 + m, N_NODES - 1);

    // A1 frags (agg, K 0..127) + A2 frags (self, K 128..255) from global, coalesced-ish
    bf16x8 a1h[4], a1l[4], a2h[4], a2l[4];
    {
        const unsigned short* r1h = Aghi + (size_t)nodec * D + quad * 8;
        const unsigned short* r1l = Aglo + (size_t)nodec * D + quad * 8;
        const unsigned short* r2h = A2hi + (size_t)nodec * D + quad * 8;
        const unsigned short* r2l = A2lo + (size_t)nodec * D + quad * 8;
        #pragma unroll
        for (int ks = 0; ks < 4; ks++) {
            a1h[ks] = *(const bf16x8*)(r1h + ks * 32);
            a1l[ks] = *(const bf16x8*)(r1l + ks * 32);
            a2h[ks] = *(const bf16x8*)(r2h + ks * 32);
            a2l[ks] = *(const bf16x8*)(r2l + ks * 32);
        }
    }

    // ---- GEMM over 4 f-quarters (Whi staged 16 KB at a time) ----
    #pragma unroll 1
    for (int fq = 0; fq < 4; fq++) {
        const int f0 = fq * 32;
        if (fq) __syncthreads();
        #pragma unroll
        for (int itS = 0; itS < 2; itS++) {
            int c = tid + itS * 512;                 // 1024 chunks of 16B
            int nt = c >> 9, w2 = c & 511;
            int ks = w2 >> 6, lidx = w2 & 63;
            int mm = lidx >> 2, qq = lidx & 3;
            const unsigned short* gp = Whi + (size_t)(f0 + nt * 16 + mm) * 256 + ks * 32 + qq * 8;
            *(bf16x8*)&Wl[(size_t)c * 8] = *(const bf16x8*)gp;
        }
        __syncthreads();

        int f = f0 + tp * 16 + m;
        const unsigned short* wlorow = Wlo + (size_t)f * 256 + quad * 8;
        f32x4 acc0 = {0.f, 0.f, 0.f, 0.f};
        f32x4 acc1 = {0.f, 0.f, 0.f, 0.f};
        f32x4 acc2 = {0.f, 0.f, 0.f, 0.f};
        #pragma unroll
        for (int ks = 0; ks < 8; ks++) {
            bf16x8 bh = *(const bf16x8*)&Wl[(size_t)(((tp * 8 + ks) << 6) + (m * 4 + quad)) * 8];
            bf16x8 bl = *(const bf16x8*)(wlorow + ks * 32);
            bf16x8 ah = (ks < 4) ? a1h[ks] : a2h[ks - 4];
            bf16x8 al = (ks < 4) ? a1l[ks] : a2l[ks - 4];
            acc0 = __builtin_amdgcn_mfma_f32_16x16x32_bf16(ah, bh, acc0, 0, 0, 0);
            acc1 = __builtin_amdgcn_mfma_f32_16x16x32_bf16(ah, bl, acc1, 0, 0, 0);
            acc2 = __builtin_amdgcn_mfma_f32_16x16x32_bf16(al, bh, acc2, 0, 0, 0);
        }
        float bv = bias[f];
        #pragma unroll
        for (int r = 0; r < 4; r++) {
            int lrow = gg * 16 + quad * 4 + r;
            int nrow = nb0 + lrow;
            float v = fmaxf((acc0[r] + (acc1[r] + acc2[r])) + bv, 0.f);
            unsigned short h = f2bf(v);
            unsigned short l = f2bf(v - bf2f(h));
            if (FINAL) {
                ((unsigned short*)Ah)[lrow * 136 + f] = h;
                ((unsigned short*)Al)[lrow * 136 + f] = l;
            } else if (nrow < N_NODES) {
                Ohi[(size_t)nrow * D + f] = h;
                Olo[(size_t)nrow * D + f] = l;
            }
        }
    }

    if (!FINAL) return;

    // ---- classifier GEMM (48 cols) + log_softmax ----
    __syncthreads();   // h2 LDS complete
    bf16x8 a3h[4], a3l[4];
    #pragma unroll
    for (int ks = 0; ks < 4; ks++) {
        int ad = (gg * 16 + m) * 136 + ks * 32 + quad * 8;
        a3h[ks] = *(const bf16x8*)((const unsigned short*)Ah + ad);
        a3l[ks] = *(const bf16x8*)((const unsigned short*)Al + ad);
    }
    // tp=0 -> tiles 0,1 (cols 0..31); tp=1 -> tile 2 (cols 32..47)
    const int ntiles = (tp == 0) ? 2 : 1;
    float res[2][4];
    #pragma unroll
    for (int t = 0; t < 2; t++) {
        if (t >= ntiles) break;
        int nt = (tp == 0) ? t : 2;
        int f = nt * 16 + m;
        const unsigned short* whirow = WLhi + (size_t)f * 256 + quad * 8;
        const unsigned short* wlorow = WLlo + (size_t)f * 256 + quad * 8;
        f32x4 acc0 = {0.f, 0.f, 0.f, 0.f};
        f32x4 acc1 = {0.f, 0.f, 0.f, 0.f};
        f32x4 acc2 = {0.f, 0.f, 0.f, 0.f};
        #pragma unroll
        for (int ks = 0; ks < 8; ks++) {
            bf16x8 bh = *(const bf16x8*)(whirow + ks * 32);
            bf16x8 bl = *(const bf16x8*)(wlorow + ks * 32);
            bf16x8 ah = (ks < 4) ? a2h[ks] : a3h[ks - 4];   // A = [h1 | h2]
            bf16x8 al = (ks < 4) ? a2l[ks] : a3l[ks - 4];
            acc0 = __builtin_amdgcn_mfma_f32_16x16x32_bf16(ah, bh, acc0, 0, 0, 0);
            acc1 = __builtin_amdgcn_mfma_f32_16x16x32_bf16(ah, bl, acc1, 0, 0, 0);
            acc2 = __builtin_amdgcn_mfma_f32_16x16x32_bf16(al, bh, acc2, 0, 0, 0);
        }
        float bv = (f < 40) ? blin[f] : 0.f;
        #pragma unroll
        for (int r = 0; r < 4; r++) res[t][r] = (acc0[r] + (acc1[r] + acc2[r])) + bv;
    }
    #pragma unroll
    for (int r = 0; r < 4; r++) {
        float pm = -INFINITY;
        #pragma unroll
        for (int t = 0; t < 2; t++) {
            if (t >= ntiles) break;
            int f = ((tp == 0) ? t : 2) * 16 + m;
            if (f < 40) pm = fmaxf(pm, res[t][r]);
        }
        #pragma unroll
        for (int o = 8; o > 0; o >>= 1) pm = fmaxf(pm, __shfl_xor(pm, o, 64));
        if (m == 0) stats[tp * 64 + gg * 16 + quad * 4 + r] = pm;
    }
    __syncthreads();
    float gm[4];
    #pragma unroll
    for (int r = 0; r < 4; r++) {
        int row = gg * 16 + quad * 4 + r;
        gm[r] = fmaxf(stats[row], stats[64 + row]);
        float ps = 0.f;
        #pragma unroll
        for (int t = 0; t < 2; t++) {
            if (t >= ntiles) break;
            int f = ((tp == 0) ? t : 2) * 16 + m;
            if (f < 40) ps += expf(res[t][r] - gm[r]);
        }
        #pragma unroll
        for (int o = 8; o > 0; o >>= 1) ps += __shfl_xor(ps, o, 64);
        if (m == 0) stats[128 + tp * 64 + row] = ps;
    }
    __syncthreads();
    #pragma unroll
    for (int r = 0; r < 4; r++) {
        int row = gg * 16 + quad * 4 + r;
        int nrow = nb0 + row;
        if (nrow >= N_NODES) continue;
        float lse = gm[r] + logf(stats[128 + row] + stats[192 + row]);
        #pragma unroll
        for (int t = 0; t < 2; t++) {
            if (t >= ntiles) break;
            int f = ((tp == 0) ? t : 2) * 16 + m;
            if (f < 40) out[(size_t)nrow * 40 + f] = res[t][r] - lse;
        }
    }
}

extern "C" void kernel_launch(void* const* d_in, const int* in_sizes, int n_in,
                              void* d_out, int out_size, void* d_ws, size_t ws_size,
                              hipStream_t stream) {
    const float* x     = (const float*)d_in[0];
    const int*   ei    = (const int*)d_in[1];
    const int*   src   = ei;
    const int*   dst   = ei + N_EDGES;
    const float* W1_l  = (const float*)d_in[2];
    const float* b1_l  = (const float*)d_in[3];
    const float* W1_r  = (const float*)d_in[4];
    const float* W2_l  = (const float*)d_in[5];
    const float* b2_l  = (const float*)d_in[6];
    const float* W2_r  = (const float*)d_in[7];
    const float* W_lin = (const float*)d_in[8];
    const float* b_lin = (const float*)d_in[9];
    float* out = (float*)d_out;

    const size_t nd = (size_t)N_NODES * D;
    unsigned short* xhi  = (unsigned short*)d_ws;
    unsigned short* xlo  = xhi + nd;
    unsigned short* h1hi = xlo + nd;
    unsigned short* h1lo = h1hi + nd;
    unsigned short* W1hi = h1lo + nd;                // 128*256 bf16 each
    unsigned short* W1lo = W1hi + 128 * 256;
    unsigned short* W2hi = W1lo + 128 * 256;
    unsigned short* W2lo = W2hi + 128 * 256;
    unsigned short* WLhi = W2lo + 128 * 256;         // 48*256
    unsigned short* WLlo = WLhi + 48 * 256;
    int* deg    = (int*)(WLlo + 48 * 256);
    int* rowptr = deg + N_NODES;                     // N_NODES+1
    int* rank   = rowptr + N_NODES + 1;              // N_EDGES
    int* srcs_sorted = rank + N_EDGES;               // N_EDGES
    int* bsum   = srcs_sorted + N_EDGES;             // NBLK
    unsigned short* aghi = (unsigned short*)(bsum + NBLK);   // agg planes (reused both layers)
    unsigned short* aglo = aghi + nd;

    // ---- prep (casts/splits) + degree/rank histogram in one dispatch ----
    hipMemsetAsync(deg, 0, N_NODES * sizeof(int), stream);
    prep_deg_kernel<<<9551, 256, 0, stream>>>(dst, deg, rank, x, W1_l, W1_r, W2_l, W2_r, W_lin,
                                              xhi, xlo, W1hi, W1lo, W2hi, W2lo, WLhi, WLlo);

    // ---- CSR build ----
    scan_partial<<<NBLK, 256, 0, stream>>>(deg, bsum);
    scan_write<<<NBLK, 256, 0, stream>>>(deg, bsum, rowptr);
    bucket_kernel<<<(N_EDGES + 255) / 256, 256, 0, stream>>>(src, dst, rowptr, rank, srcs_sorted);

    const int lblk = (N_NODES + 63) / 64;

    // ---- layer 1 ----
    gather_mean<<<GATHER_BLOCKS, 256, 0, stream>>>(srcs_sorted, rowptr, xhi, aghi, aglo);
    gemm_layer<false><<<lblk, 512, 0, stream>>>(aghi, aglo, xhi, xlo,
                                                W1hi, W1lo, b1_l, h1hi, h1lo,
                                                nullptr, nullptr, nullptr, nullptr);
    // ---- layer 2 + classifier + log_softmax ----
    gather_mean<<<GATHER_BLOCKS, 256, 0, stream>>>(srcs_sorted, rowptr, h1hi, aghi, aglo);
    gemm_layer<true><<<lblk, 512, 0, stream>>>(aghi, aglo, h1hi, h1lo,
                                               W2hi, W2lo, b2_l, nullptr, nullptr,
                                               WLhi, WLlo, b_lin, out);
}